// Round 1
// baseline (506.172 us; speedup 1.0000x reference)
//
#include <hip/hip_runtime.h>

#define D 128
#define EDGE_DIM 6
#define LN_EPS 1e-5f

// ---------- kernel 1: Wc = We @ Wm2, bc = be @ Wm2 + bm ----------
// Wm2 = rows 128..255 of Wm ([256,128] row-major).
__global__ void prep_wc(const float* __restrict__ We, const float* __restrict__ be,
                        const float* __restrict__ Wm, const float* __restrict__ bm,
                        float* __restrict__ Wc, float* __restrict__ bc) {
    int d = threadIdx.x;  // 0..127
    float acc[EDGE_DIM] = {0.f, 0.f, 0.f, 0.f, 0.f, 0.f};
    float accb = 0.f;
    for (int j = 0; j < D; ++j) {
        float wm2 = Wm[(D + j) * D + d];
        accb = fmaf(be[j], wm2, accb);
#pragma unroll
        for (int k = 0; k < EDGE_DIM; ++k)
            acc[k] = fmaf(We[k * D + j], wm2, acc[k]);
    }
#pragma unroll
    for (int k = 0; k < EDGE_DIM; ++k) Wc[k * D + d] = acc[k];
    bc[d] = accb + bm[d];
}

// ---------- kernel 2: out[n][d] = bias[d] + sum_k A[n][k] * W[k][d] ----------
// 128 threads; thread d holds column W[:,d] in 128 VGPRs; x rows staged in LDS,
// consumed via float4 broadcast reads (VALU-bound, ~1 ds_read_b128 / 4 FMA).
__global__ __launch_bounds__(128)
void gemm128(const float* __restrict__ A, const float* __restrict__ W,
             const float* __restrict__ bias, float* __restrict__ out, int nrows) {
    const int d = threadIdx.x;
    float w[D];
#pragma unroll
    for (int k = 0; k < D; ++k) w[k] = W[k * D + d];
    const float b = bias ? bias[d] : 0.0f;

    __shared__ float4 sX[8 * 32];  // 8 rows x 128 floats = 4 KB
    const float4* A4 = reinterpret_cast<const float4*>(A);
    const int ntiles = (nrows + 7) / 8;

    for (int tile = blockIdx.x; tile < ntiles; tile += gridDim.x) {
        const int base = tile * 256;            // float4 units
        const int rem4 = nrows * 32 - base;
        sX[d]       = (d < rem4)       ? A4[base + d]       : make_float4(0.f, 0.f, 0.f, 0.f);
        sX[d + 128] = (d + 128 < rem4) ? A4[base + d + 128] : make_float4(0.f, 0.f, 0.f, 0.f);
        __syncthreads();
#pragma unroll
        for (int n = 0; n < 8; ++n) {
            const int rowi = tile * 8 + n;
            float acc = b;
#pragma unroll
            for (int k4 = 0; k4 < 32; ++k4) {
                float4 xv = sX[n * 32 + k4];
                acc = fmaf(xv.x, w[4 * k4 + 0], acc);
                acc = fmaf(xv.y, w[4 * k4 + 1], acc);
                acc = fmaf(xv.z, w[4 * k4 + 2], acc);
                acc = fmaf(xv.w, w[4 * k4 + 3], acc);
            }
            if (rowi < nrows) out[(size_t)rowi * D + d] = acc;
        }
        __syncthreads();
    }
}

// ---------- kernel 3: per-edge message + scatter ----------
// msg = relu(h[col] + edge_attr[e] @ Wc + bc); agg[row] += msg; deg[row] += 1
__global__ __launch_bounds__(256)
void edge_scatter(const float* __restrict__ h, const float* __restrict__ ea,
                  const int* __restrict__ ei, int E,
                  const float* __restrict__ Wc, const float* __restrict__ bc,
                  float* __restrict__ agg, float* __restrict__ deg) {
    __shared__ float sWc[EDGE_DIM * D];
    __shared__ float sbc[D];
    for (int i = threadIdx.x; i < EDGE_DIM * D; i += 256) sWc[i] = Wc[i];
    if (threadIdx.x < D) sbc[threadIdx.x] = bc[threadIdx.x];
    __syncthreads();

    const int d = threadIdx.x & (D - 1);
    const int sub = threadIdx.x >> 7;  // 0/1: two edges per block-iteration
    for (int e = blockIdx.x * 2 + sub; e < E; e += gridDim.x * 2) {
        const int row = ei[e];
        const int col = ei[E + e];
        float v = sbc[d] + h[(size_t)col * D + d];
#pragma unroll
        for (int k = 0; k < EDGE_DIM; ++k)
            v = fmaf(ea[(size_t)e * EDGE_DIM + k], sWc[k * D + d], v);
        v = fmaxf(v, 0.0f);
        atomicAdd(&agg[(size_t)row * D + d], v);
        if (d == 0) atomicAdd(&deg[row], 1.0f);
    }
}

// ---------- kernel 4: out = LN(agg/max(deg,1) + x_t) * gamma + beta ----------
// One wave per node; lane holds dims (2l, 2l+1); in-place on agg (= d_out).
__global__ __launch_bounds__(256)
void finalize_ln(float* __restrict__ agg, const float* __restrict__ xt,
                 const float* __restrict__ deg, const float* __restrict__ gamma,
                 const float* __restrict__ beta, int nrows) {
    const int wave = threadIdx.x >> 6;
    const int lane = threadIdx.x & 63;
    for (int n = blockIdx.x * 4 + wave; n < nrows; n += gridDim.x * 4) {
        const float2* ar = reinterpret_cast<const float2*>(agg + (size_t)n * D);
        const float2* xr = reinterpret_cast<const float2*>(xt + (size_t)n * D);
        float2 a = ar[lane];
        float2 x = xr[lane];
        const float inv = 1.0f / fmaxf(deg[n], 1.0f);
        float o0 = fmaf(a.x, inv, x.x);
        float o1 = fmaf(a.y, inv, x.y);
        float s = o0 + o1;
        float sq = o0 * o0 + o1 * o1;
#pragma unroll
        for (int off = 32; off; off >>= 1) {
            s += __shfl_xor(s, off);
            sq += __shfl_xor(sq, off);
        }
        const float mean = s * (1.0f / D);
        const float var = sq * (1.0f / D) - mean * mean;
        const float rstd = rsqrtf(var + LN_EPS);
        float2 g = reinterpret_cast<const float2*>(gamma)[lane];
        float2 bb = reinterpret_cast<const float2*>(beta)[lane];
        float2 r;
        r.x = (o0 - mean) * rstd * g.x + bb.x;
        r.y = (o1 - mean) * rstd * g.y + bb.y;
        reinterpret_cast<float2*>(agg + (size_t)n * D)[lane] = r;
    }
}

extern "C" void kernel_launch(void* const* d_in, const int* in_sizes, int n_in,
                              void* d_out, int out_size, void* d_ws, size_t ws_size,
                              hipStream_t stream) {
    const float* x     = (const float*)d_in[0];
    const float* eattr = (const float*)d_in[1];
    const float* Wn    = (const float*)d_in[2];
    const float* bn    = (const float*)d_in[3];
    const float* We    = (const float*)d_in[4];
    const float* be    = (const float*)d_in[5];
    const float* Wm    = (const float*)d_in[6];
    const float* bm    = (const float*)d_in[7];
    const float* gamma = (const float*)d_in[8];
    const float* beta  = (const float*)d_in[9];
    const int*   ei    = (const int*)d_in[10];

    const int N = in_sizes[0] / D;
    const int E = in_sizes[10] / 2;

    float* agg = (float*)d_out;  // use d_out as the aggregation buffer

    char* ws = (char*)d_ws;
    float* xt = (float*)ws;  ws += (size_t)N * D * sizeof(float);
    float* h  = (float*)ws;  ws += (size_t)N * D * sizeof(float);
    float* dg = (float*)ws;  ws += (size_t)N * sizeof(float);
    float* Wc = (float*)ws;  ws += (size_t)EDGE_DIM * D * sizeof(float);
    float* bc = (float*)ws;  ws += (size_t)D * sizeof(float);

    hipMemsetAsync(agg, 0, (size_t)N * D * sizeof(float), stream);
    hipMemsetAsync(dg, 0, (size_t)N * sizeof(float), stream);

    prep_wc<<<1, 128, 0, stream>>>(We, be, Wm, bm, Wc, bc);
    gemm128<<<2048, 128, 0, stream>>>(x, Wn, bn, xt, N);        // x_t = x@Wn + bn
    gemm128<<<2048, 128, 0, stream>>>(xt, Wm, nullptr, h, N);   // h = x_t@Wm1 (Wm rows 0..127)
    edge_scatter<<<8192, 256, 0, stream>>>(h, eattr, ei, E, Wc, bc, agg, dg);
    finalize_ln<<<4096, 256, 0, stream>>>(agg, xt, dg, gamma, beta, N);
}

// Round 2
// 329.884 us; speedup vs baseline: 1.5344x; 1.5344x over previous
//
#include <hip/hip_runtime.h>

#define D 128
#define EDGE_DIM 6
#define LN_EPS 1e-5f

// ---------- kernel 1: Wc = We @ Wm2, bc = be @ Wm2 + bm ----------
__global__ void prep_wc(const float* __restrict__ We, const float* __restrict__ be,
                        const float* __restrict__ Wm, const float* __restrict__ bm,
                        float* __restrict__ Wc, float* __restrict__ bc) {
    int d = threadIdx.x;  // 0..127
    float acc[EDGE_DIM] = {0.f, 0.f, 0.f, 0.f, 0.f, 0.f};
    float accb = 0.f;
    for (int j = 0; j < D; ++j) {
        float wm2 = Wm[(D + j) * D + d];
        accb = fmaf(be[j], wm2, accb);
#pragma unroll
        for (int k = 0; k < EDGE_DIM; ++k)
            acc[k] = fmaf(We[k * D + j], wm2, acc[k]);
    }
#pragma unroll
    for (int k = 0; k < EDGE_DIM; ++k) Wc[k * D + d] = acc[k];
    bc[d] = accb + bm[d];
}

// ---------- kernel 2: out[n][d] = bias[d] + sum_k A[n][k] * W[k][d] ----------
__global__ __launch_bounds__(128)
void gemm128(const float* __restrict__ A, const float* __restrict__ W,
             const float* __restrict__ bias, float* __restrict__ out, int nrows) {
    const int d = threadIdx.x;
    float w[D];
#pragma unroll
    for (int k = 0; k < D; ++k) w[k] = W[k * D + d];
    const float b = bias ? bias[d] : 0.0f;

    __shared__ float4 sX[8 * 32];
    const float4* A4 = reinterpret_cast<const float4*>(A);
    const int ntiles = (nrows + 7) / 8;

    for (int tile = blockIdx.x; tile < ntiles; tile += gridDim.x) {
        const int base = tile * 256;
        const int rem4 = nrows * 32 - base;
        sX[d]       = (d < rem4)       ? A4[base + d]       : make_float4(0.f, 0.f, 0.f, 0.f);
        sX[d + 128] = (d + 128 < rem4) ? A4[base + d + 128] : make_float4(0.f, 0.f, 0.f, 0.f);
        __syncthreads();
#pragma unroll
        for (int n = 0; n < 8; ++n) {
            const int rowi = tile * 8 + n;
            float acc = b;
#pragma unroll
            for (int k4 = 0; k4 < 32; ++k4) {
                float4 xv = sX[n * 32 + k4];
                acc = fmaf(xv.x, w[4 * k4 + 0], acc);
                acc = fmaf(xv.y, w[4 * k4 + 1], acc);
                acc = fmaf(xv.z, w[4 * k4 + 2], acc);
                acc = fmaf(xv.w, w[4 * k4 + 3], acc);
            }
            if (rowi < nrows) out[(size_t)rowi * D + d] = acc;
        }
        __syncthreads();
    }
}

// ---------- kernel 3: histogram of rows ----------
__global__ void hist_rows(const int* __restrict__ ei, int E, int* __restrict__ cnt) {
    int i = blockIdx.x * blockDim.x + threadIdx.x;
    if (i < E) atomicAdd(&cnt[ei[i]], 1);
}

// ---------- kernel 4: single-block exclusive scan (N up to ~1M) ----------
__global__ __launch_bounds__(1024)
void scan_excl(const int* __restrict__ cnt, int* __restrict__ start, int n) {
    __shared__ int wsum[16];
    const int tid = threadIdx.x, lane = tid & 63, wid = tid >> 6;
    int carry = 0;
    for (int base = 0; base < n; base += 1024) {
        int i = base + tid;
        int v = (i < n) ? cnt[i] : 0;
        int x = v;
#pragma unroll
        for (int off = 1; off < 64; off <<= 1) {
            int t = __shfl_up(x, off);
            if (lane >= off) x += t;
        }
        if (lane == 63) wsum[wid] = x;
        __syncthreads();
        if (wid == 0) {
            int w = (lane < 16) ? wsum[lane] : 0;
#pragma unroll
            for (int off = 1; off < 16; off <<= 1) {
                int t = __shfl_up(w, off);
                if (lane >= off) w += t;
            }
            if (lane < 16) wsum[lane] = w;
        }
        __syncthreads();
        int woff = (wid > 0) ? wsum[wid - 1] : 0;
        if (i < n) start[i] = carry + x + woff - v;
        carry += wsum[15];
        __syncthreads();
    }
}

// ---------- kernel 5: scatter edge ids into CSR order ----------
__global__ void scatter_perm(const int* __restrict__ ei, int E,
                             const int* __restrict__ start, int* __restrict__ cur,
                             int* __restrict__ perm) {
    int e = blockIdx.x * blockDim.x + threadIdx.x;
    if (e < E) {
        int row = ei[e];
        int pos = start[row] + atomicAdd(&cur[row], 1);
        perm[pos] = e;
    }
}

// ---------- kernel 6: per-node gather-aggregate + residual + LayerNorm ----------
// One wave per node; lane holds dims (2l, 2l+1).
__global__ __launch_bounds__(256)
void aggregate_ln(const float* __restrict__ h, const float* __restrict__ ea,
                  const int* __restrict__ ei, int E,
                  const int* __restrict__ start, const int* __restrict__ cnt,
                  const int* __restrict__ perm,
                  const float* __restrict__ Wc, const float* __restrict__ bc,
                  const float* __restrict__ xt,
                  const float* __restrict__ gamma, const float* __restrict__ beta,
                  float* __restrict__ out, int nnode) {
    const int lane = threadIdx.x & 63;
    const int wid = threadIdx.x >> 6;

    float2 wc[EDGE_DIM], bc2;
#pragma unroll
    for (int k = 0; k < EDGE_DIM; ++k)
        wc[k] = reinterpret_cast<const float2*>(Wc)[k * 64 + lane];
    bc2 = reinterpret_cast<const float2*>(bc)[lane];
    const float2 g = reinterpret_cast<const float2*>(gamma)[lane];
    const float2 bb = reinterpret_cast<const float2*>(beta)[lane];
    const float2* h2 = reinterpret_cast<const float2*>(h);

    for (int n = blockIdx.x * 4 + wid; n < nnode; n += gridDim.x * 4) {
        const int s = start[n];
        const int c = cnt[n];
        float ax = 0.f, ay = 0.f;
        for (int ibase = 0; ibase < c; ibase += 64) {
            const int m = min(64, c - ibase);
            int eid = 0, colv = 0;
            if (lane < m) {
                eid = perm[s + ibase + lane];
                colv = ei[E + eid];
            }
            for (int i = 0; i < m; ++i) {
                const int e = __shfl(eid, i);
                const int col = __shfl(colv, i);
                float2 hv = h2[(size_t)col * 64 + lane];
                const float2* ep = reinterpret_cast<const float2*>(ea + (size_t)e * EDGE_DIM);
                float2 e01 = ep[0], e23 = ep[1], e45 = ep[2];
                float vx = bc2.x + hv.x, vy = bc2.y + hv.y;
                vx = fmaf(e01.x, wc[0].x, vx); vy = fmaf(e01.x, wc[0].y, vy);
                vx = fmaf(e01.y, wc[1].x, vx); vy = fmaf(e01.y, wc[1].y, vy);
                vx = fmaf(e23.x, wc[2].x, vx); vy = fmaf(e23.x, wc[2].y, vy);
                vx = fmaf(e23.y, wc[3].x, vx); vy = fmaf(e23.y, wc[3].y, vy);
                vx = fmaf(e45.x, wc[4].x, vx); vy = fmaf(e45.x, wc[4].y, vy);
                vx = fmaf(e45.y, wc[5].x, vx); vy = fmaf(e45.y, wc[5].y, vy);
                ax += fmaxf(vx, 0.f);
                ay += fmaxf(vy, 0.f);
            }
        }
        const float inv = 1.0f / fmaxf((float)c, 1.0f);
        float2 xv = reinterpret_cast<const float2*>(xt)[(size_t)n * 64 + lane];
        float o0 = fmaf(ax, inv, xv.x);
        float o1 = fmaf(ay, inv, xv.y);
        float s1 = o0 + o1, s2 = o0 * o0 + o1 * o1;
#pragma unroll
        for (int off = 32; off; off >>= 1) {
            s1 += __shfl_xor(s1, off);
            s2 += __shfl_xor(s2, off);
        }
        const float mean = s1 * (1.0f / D);
        const float var = s2 * (1.0f / D) - mean * mean;
        const float rstd = rsqrtf(var + LN_EPS);
        float2 r;
        r.x = (o0 - mean) * rstd * g.x + bb.x;
        r.y = (o1 - mean) * rstd * g.y + bb.y;
        reinterpret_cast<float2*>(out)[(size_t)n * 64 + lane] = r;
    }
}

extern "C" void kernel_launch(void* const* d_in, const int* in_sizes, int n_in,
                              void* d_out, int out_size, void* d_ws, size_t ws_size,
                              hipStream_t stream) {
    const float* x     = (const float*)d_in[0];
    const float* eattr = (const float*)d_in[1];
    const float* Wn    = (const float*)d_in[2];
    const float* bn    = (const float*)d_in[3];
    const float* We    = (const float*)d_in[4];
    const float* be    = (const float*)d_in[5];
    const float* Wm    = (const float*)d_in[6];
    const float* bm    = (const float*)d_in[7];
    const float* gamma = (const float*)d_in[8];
    const float* beta  = (const float*)d_in[9];
    const int*   ei    = (const int*)d_in[10];

    const int N = in_sizes[0] / D;
    const int E = in_sizes[10] / 2;

    char* ws = (char*)d_ws;
    float* xt   = (float*)ws;  ws += (size_t)N * D * sizeof(float);
    float* h    = (float*)ws;  ws += (size_t)N * D * sizeof(float);
    int*   cnt  = (int*)ws;    ws += (size_t)N * sizeof(int);
    int*   startv = (int*)ws;  ws += (size_t)N * sizeof(int);
    int*   cur  = (int*)ws;    ws += (size_t)N * sizeof(int);
    int*   perm = (int*)ws;    ws += (size_t)E * sizeof(int);
    float* Wc   = (float*)ws;  ws += (size_t)EDGE_DIM * D * sizeof(float);
    float* bc   = (float*)ws;  ws += (size_t)D * sizeof(float);

    hipMemsetAsync(cnt, 0, (size_t)N * sizeof(int), stream);
    hipMemsetAsync(cur, 0, (size_t)N * sizeof(int), stream);

    prep_wc<<<1, 128, 0, stream>>>(We, be, Wm, bm, Wc, bc);
    gemm128<<<2048, 128, 0, stream>>>(x, Wn, bn, xt, N);       // x_t = x@Wn + bn
    gemm128<<<2048, 128, 0, stream>>>(xt, Wm, nullptr, h, N);  // h = x_t@Wm1
    hist_rows<<<(E + 255) / 256, 256, 0, stream>>>(ei, E, cnt);
    scan_excl<<<1, 1024, 0, stream>>>(cnt, startv, N);
    scatter_perm<<<(E + 255) / 256, 256, 0, stream>>>(ei, E, startv, cur, perm);
    aggregate_ln<<<(N + 3) / 4, 256, 0, stream>>>(h, eattr, ei, E, startv, cnt, perm,
                                                  Wc, bc, xt, gamma, beta,
                                                  (float*)d_out, N);
}

// Round 3
// 266.584 us; speedup vs baseline: 1.8987x; 1.2374x over previous
//
#include <hip/hip_runtime.h>
#include <hip/hip_bf16.h>

#define D 128
#define EDGE_DIM 6
#define LN_EPS 1e-5f

// ---------- kernel 1: Wc = We @ Wm2, bc = be @ Wm2 + bm (8 waves) ----------
__global__ __launch_bounds__(1024)
void prep_wc(const float* __restrict__ We, const float* __restrict__ be,
             const float* __restrict__ Wm, const float* __restrict__ bm,
             float* __restrict__ Wc, float* __restrict__ bc) {
    const int d = threadIdx.x & (D - 1);   // 0..127
    const int grp = threadIdx.x >> 7;      // 0..7, each handles 16 j's
    __shared__ float sred[7][8][D];
    float acc[EDGE_DIM] = {0.f, 0.f, 0.f, 0.f, 0.f, 0.f};
    float accb = 0.f;
    for (int j = grp * 16; j < grp * 16 + 16; ++j) {
        float wm2 = Wm[(D + j) * D + d];
        accb = fmaf(be[j], wm2, accb);
#pragma unroll
        for (int k = 0; k < EDGE_DIM; ++k)
            acc[k] = fmaf(We[k * D + j], wm2, acc[k]);
    }
#pragma unroll
    for (int k = 0; k < EDGE_DIM; ++k) sred[k][grp][d] = acc[k];
    sred[6][grp][d] = accb;
    __syncthreads();
    if (threadIdx.x < D) {
#pragma unroll
        for (int k = 0; k < EDGE_DIM; ++k) {
            float s = 0.f;
#pragma unroll
            for (int g = 0; g < 8; ++g) s += sred[k][g][d];
            Wc[k * D + d] = s;
        }
        float s = 0.f;
#pragma unroll
        for (int g = 0; g < 8; ++g) s += sred[6][g][d];
        bc[d] = s + bm[d];
    }
}

// ---------- kernel 2: out[n][d] = bias[d] + sum_k A[n][k] * W[k][d] ----------
// BF16OUT: write __hip_bfloat16 instead of float.
template <bool BF16OUT>
__global__ __launch_bounds__(128)
void gemm128(const float* __restrict__ A, const float* __restrict__ W,
             const float* __restrict__ bias, void* __restrict__ out, int nrows) {
    const int d = threadIdx.x;
    float w[D];
#pragma unroll
    for (int k = 0; k < D; ++k) w[k] = W[k * D + d];
    const float b = bias ? bias[d] : 0.0f;

    __shared__ float4 sX[8 * 32];
    const float4* A4 = reinterpret_cast<const float4*>(A);
    const int ntiles = (nrows + 7) / 8;

    for (int tile = blockIdx.x; tile < ntiles; tile += gridDim.x) {
        const int base = tile * 256;
        const int rem4 = nrows * 32 - base;
        sX[d]       = (d < rem4)       ? A4[base + d]       : make_float4(0.f, 0.f, 0.f, 0.f);
        sX[d + 128] = (d + 128 < rem4) ? A4[base + d + 128] : make_float4(0.f, 0.f, 0.f, 0.f);
        __syncthreads();
#pragma unroll
        for (int n = 0; n < 8; ++n) {
            const int rowi = tile * 8 + n;
            float acc = b;
#pragma unroll
            for (int k4 = 0; k4 < 32; ++k4) {
                float4 xv = sX[n * 32 + k4];
                acc = fmaf(xv.x, w[4 * k4 + 0], acc);
                acc = fmaf(xv.y, w[4 * k4 + 1], acc);
                acc = fmaf(xv.z, w[4 * k4 + 2], acc);
                acc = fmaf(xv.w, w[4 * k4 + 3], acc);
            }
            if (rowi < nrows) {
                if (BF16OUT)
                    ((__hip_bfloat16*)out)[(size_t)rowi * D + d] = __hip_bfloat16(acc);
                else
                    ((float*)out)[(size_t)rowi * D + d] = acc;
            }
        }
        __syncthreads();
    }
}

// ---------- kernel 3: histogram of rows ----------
__global__ void hist_rows(const int* __restrict__ ei, int E, int* __restrict__ cnt) {
    int i = blockIdx.x * blockDim.x + threadIdx.x;
    if (i < E) atomicAdd(&cnt[ei[i]], 1);
}

// ---------- kernel 4: multi-block scan; block base via atomic cursor ----------
// Segments need only be disjoint with correct sizes (CSR order across nodes
// is irrelevant to the final per-node sums), so a nondeterministic block base
// is semantically fine.
__global__ __launch_bounds__(1024)
void scan_block_atomic(const int* __restrict__ cnt, int* __restrict__ start,
                       int* __restrict__ cursor, int n) {
    __shared__ int wsum[16];
    __shared__ int sbase;
    const int tid = threadIdx.x, lane = tid & 63, wid = tid >> 6;
    const int i = blockIdx.x * 1024 + tid;
    const int v = (i < n) ? cnt[i] : 0;
    int x = v;
#pragma unroll
    for (int off = 1; off < 64; off <<= 1) {
        int t = __shfl_up(x, off);
        if (lane >= off) x += t;
    }
    if (lane == 63) wsum[wid] = x;
    __syncthreads();
    if (wid == 0) {
        int w = (lane < 16) ? wsum[lane] : 0;
#pragma unroll
        for (int off = 1; off < 16; off <<= 1) {
            int t = __shfl_up(w, off);
            if (lane >= off) w += t;
        }
        if (lane < 16) wsum[lane] = w;
    }
    __syncthreads();
    const int total = wsum[15];
    if (tid == 0) sbase = atomicAdd(cursor, total);
    __syncthreads();
    const int woff = (wid > 0) ? wsum[wid - 1] : 0;
    if (i < n) start[i] = sbase + woff + x - v;
}

// ---------- kernel 5: scatter edge ids into CSR order ----------
__global__ void scatter_perm(const int* __restrict__ ei, int E,
                             const int* __restrict__ start, int* __restrict__ cur,
                             int* __restrict__ perm) {
    int e = blockIdx.x * blockDim.x + threadIdx.x;
    if (e < E) {
        int row = ei[e];
        int pos = start[row] + atomicAdd(&cur[row], 1);
        perm[pos] = e;
    }
}

// ---------- kernel 6: per-node gather-aggregate + residual + LayerNorm ----------
// One wave per node; lane holds dims (2l, 2l+1); h gathered as bf16 (256B/edge).
__global__ __launch_bounds__(256)
void aggregate_ln(const unsigned int* __restrict__ h, const float* __restrict__ ea,
                  const int* __restrict__ ei, int E,
                  const int* __restrict__ start, const int* __restrict__ cnt,
                  const int* __restrict__ perm,
                  const float* __restrict__ Wc, const float* __restrict__ bc,
                  const float* __restrict__ xt,
                  const float* __restrict__ gamma, const float* __restrict__ beta,
                  float* __restrict__ out, int nnode) {
    const int lane = threadIdx.x & 63;
    const int wid = threadIdx.x >> 6;

    float2 wc[EDGE_DIM], bc2;
#pragma unroll
    for (int k = 0; k < EDGE_DIM; ++k)
        wc[k] = reinterpret_cast<const float2*>(Wc)[k * 64 + lane];
    bc2 = reinterpret_cast<const float2*>(bc)[lane];
    const float2 g = reinterpret_cast<const float2*>(gamma)[lane];
    const float2 bb = reinterpret_cast<const float2*>(beta)[lane];

    for (int n = blockIdx.x * 4 + wid; n < nnode; n += gridDim.x * 4) {
        const int s = start[n];
        const int c = cnt[n];
        float ax = 0.f, ay = 0.f;
        for (int ibase = 0; ibase < c; ibase += 64) {
            const int m = min(64, c - ibase);
            int eid = 0, colv = 0;
            if (lane < m) {
                eid = perm[s + ibase + lane];
                colv = ei[E + eid];
            }
#pragma unroll 2
            for (int i = 0; i < m; ++i) {
                const int e = __shfl(eid, i);
                const int col = __shfl(colv, i);
                const unsigned int hv = h[(size_t)col * 64 + lane];  // 2 bf16
                const float hx = __uint_as_float(hv << 16);
                const float hy = __uint_as_float(hv & 0xffff0000u);
                const float2* ep = reinterpret_cast<const float2*>(ea + (size_t)e * EDGE_DIM);
                float2 e01 = ep[0], e23 = ep[1], e45 = ep[2];
                float vx = bc2.x + hx, vy = bc2.y + hy;
                vx = fmaf(e01.x, wc[0].x, vx); vy = fmaf(e01.x, wc[0].y, vy);
                vx = fmaf(e01.y, wc[1].x, vx); vy = fmaf(e01.y, wc[1].y, vy);
                vx = fmaf(e23.x, wc[2].x, vx); vy = fmaf(e23.x, wc[2].y, vy);
                vx = fmaf(e23.y, wc[3].x, vx); vy = fmaf(e23.y, wc[3].y, vy);
                vx = fmaf(e45.x, wc[4].x, vx); vy = fmaf(e45.x, wc[4].y, vy);
                vx = fmaf(e45.y, wc[5].x, vx); vy = fmaf(e45.y, wc[5].y, vy);
                ax += fmaxf(vx, 0.f);
                ay += fmaxf(vy, 0.f);
            }
        }
        const float inv = 1.0f / fmaxf((float)c, 1.0f);
        float2 xv = reinterpret_cast<const float2*>(xt)[(size_t)n * 64 + lane];
        float o0 = fmaf(ax, inv, xv.x);
        float o1 = fmaf(ay, inv, xv.y);
        float s1 = o0 + o1, s2 = o0 * o0 + o1 * o1;
#pragma unroll
        for (int off = 32; off; off >>= 1) {
            s1 += __shfl_xor(s1, off);
            s2 += __shfl_xor(s2, off);
        }
        const float mean = s1 * (1.0f / D);
        const float var = s2 * (1.0f / D) - mean * mean;
        const float rstd = rsqrtf(var + LN_EPS);
        float2 r;
        r.x = (o0 - mean) * rstd * g.x + bb.x;
        r.y = (o1 - mean) * rstd * g.y + bb.y;
        reinterpret_cast<float2*>(out)[(size_t)n * 64 + lane] = r;
    }
}

extern "C" void kernel_launch(void* const* d_in, const int* in_sizes, int n_in,
                              void* d_out, int out_size, void* d_ws, size_t ws_size,
                              hipStream_t stream) {
    const float* x     = (const float*)d_in[0];
    const float* eattr = (const float*)d_in[1];
    const float* Wn    = (const float*)d_in[2];
    const float* bn    = (const float*)d_in[3];
    const float* We    = (const float*)d_in[4];
    const float* be    = (const float*)d_in[5];
    const float* Wm    = (const float*)d_in[6];
    const float* bm    = (const float*)d_in[7];
    const float* gamma = (const float*)d_in[8];
    const float* beta  = (const float*)d_in[9];
    const int*   ei    = (const int*)d_in[10];

    const int N = in_sizes[0] / D;
    const int E = in_sizes[10] / 2;

    char* ws = (char*)d_ws;
    float* xt     = (float*)ws;  ws += (size_t)N * D * sizeof(float);
    unsigned int* h = (unsigned int*)ws; ws += (size_t)N * D * sizeof(unsigned short);
    int*   cnt    = (int*)ws;    ws += (size_t)N * sizeof(int);
    int*   startv = (int*)ws;    ws += (size_t)N * sizeof(int);
    int*   cur    = (int*)ws;    ws += (size_t)N * sizeof(int);
    int*   cursor = (int*)ws;    ws += 4 * sizeof(int);
    int*   perm   = (int*)ws;    ws += (size_t)E * sizeof(int);
    float* Wc     = (float*)ws;  ws += (size_t)EDGE_DIM * D * sizeof(float);
    float* bc     = (float*)ws;  ws += (size_t)D * sizeof(float);

    hipMemsetAsync(cnt, 0, (size_t)N * sizeof(int), stream);
    hipMemsetAsync(cur, 0, (size_t)N * sizeof(int), stream);
    hipMemsetAsync(cursor, 0, 4 * sizeof(int), stream);

    prep_wc<<<1, 1024, 0, stream>>>(We, be, Wm, bm, Wc, bc);
    gemm128<false><<<2048, 128, 0, stream>>>(x, Wn, bn, xt, N);      // x_t = x@Wn + bn
    gemm128<true><<<2048, 128, 0, stream>>>(xt, Wm, nullptr, h, N);  // h = x_t@Wm1 (bf16)
    hist_rows<<<(E + 255) / 256, 256, 0, stream>>>(ei, E, cnt);
    scan_block_atomic<<<(N + 1023) / 1024, 1024, 0, stream>>>(cnt, startv, cursor, N);
    scatter_perm<<<(E + 255) / 256, 256, 0, stream>>>(ei, E, startv, cur, perm);
    aggregate_ln<<<(N + 3) / 4, 256, 0, stream>>>(h, eattr, ei, E, startv, cnt, perm,
                                                  Wc, bc, xt, gamma, beta,
                                                  (float*)d_out, N);
}